// Round 1
// baseline (686.706 us; speedup 1.0000x reference)
//
#include <hip/hip_runtime.h>

// Problem constants
#define NB 96
#define NQ 96
#define NV 197
#define NT 77
#define DK 768
#define DE 512

typedef __attribute__((ext_vector_type(8))) short s16x8;
typedef __attribute__((ext_vector_type(4))) float f32x4;

__device__ __forceinline__ unsigned short f2bf(float f) {
  union { float f; unsigned int u; } v; v.f = f;
  unsigned int u = v.u;
  unsigned int r = u + 0x7fffu + ((u >> 16) & 1u);
  return (unsigned short)(r >> 16);
}

// ---------------------------------------------------------------------------
// K0: fp32 -> bf16 conversion (for weight matrices)
// ---------------------------------------------------------------------------
__global__ __launch_bounds__(256) void cvt_bf16_kernel(
    const float* __restrict__ src, unsigned short* __restrict__ dst, int n4) {
  int i = blockIdx.x * 256 + threadIdx.x;
  if (i < n4) {
    float4 x = ((const float4*)src)[i];
    ushort4 h;
    h.x = f2bf(x.x); h.y = f2bf(x.y); h.z = f2bf(x.z); h.w = f2bf(x.w);
    ((ushort4*)dst)[i] = h;
  }
}

// ---------------------------------------------------------------------------
// K1: cls projection, fp32 exact.  One block per output row.
// out[row][c] = dot(X[row], W[c]) + bias[c]
// ---------------------------------------------------------------------------
__global__ __launch_bounds__(256) void cls_kernel(
    const float* __restrict__ X, const float* __restrict__ W,
    const float* __restrict__ bias, float* __restrict__ out) {
  __shared__ float xs[DK];
  const int row = blockIdx.x;
  const float* xr = X + (long)row * DK;
  for (int i = threadIdx.x; i < DK; i += 256) xs[i] = xr[i];
  __syncthreads();
  for (int c = threadIdx.x; c < DE; c += 256) {
    const float* wr = W + (long)c * DK;
    float s = 0.f;
    #pragma unroll 4
    for (int k = 0; k < DK; k += 4) {
      float4 w4 = *(const float4*)(wr + k);
      s += xs[k] * w4.x + xs[k + 1] * w4.y + xs[k + 2] * w4.z + xs[k + 3] * w4.w;
    }
    out[(long)row * DE + c] = s + bias[c];
  }
}

// ---------------------------------------------------------------------------
// K2: token projection + bias + l2norm, MFMA bf16.
// Block = 32 rows x all 512 cols.  Wave w owns cols [w*128, w*128+128).
// X fp32 [M x 768], Wb bf16 [512 x 768] (row=col-of-output), Y bf16 [M x 512].
// ---------------------------------------------------------------------------
__global__ __launch_bounds__(256, 2) void proj_norm_kernel(
    const float* __restrict__ X, const unsigned short* __restrict__ Wb,
    const float* __restrict__ bias, unsigned short* __restrict__ Y) {
  __shared__ __align__(16) unsigned short Ws[512 * 40];  // stride 40 elts: 2-way banks
  __shared__ __align__(16) unsigned short Xs[32 * 40];
  __shared__ float ssq_lds[4][32];

  const int tid = threadIdx.x;
  const int wave = tid >> 6;
  const int lane = tid & 63;
  const int l15 = lane & 15;
  const int quad = lane >> 4;
  const long row0 = (long)blockIdx.x * 32;

  f32x4 acc[2][8];
  #pragma unroll
  for (int m = 0; m < 2; ++m)
    #pragma unroll
    for (int n = 0; n < 8; ++n)
      acc[m][n] = (f32x4){0.f, 0.f, 0.f, 0.f};

  const int xrow = tid >> 3;  // 0..31
  const int xseg = tid & 7;   // 0..7 (4 floats each)

  for (int kc = 0; kc < DK; kc += 32) {
    __syncthreads();
    // stage W chunk: 512 cols x 32 k (bf16 direct)
    #pragma unroll
    for (int j = 0; j < 8; ++j) {
      int i = tid + j * 256;          // 0..2047, 16B chunks
      int col = i >> 2, seg = i & 3;
      uint4 d = *(const uint4*)(Wb + (long)col * DK + kc + seg * 8);
      *(uint4*)(&Ws[col * 40 + seg * 8]) = d;
    }
    // stage X chunk: 32 rows x 32 k, fp32 -> bf16
    {
      float4 x = *(const float4*)(X + (row0 + xrow) * DK + kc + xseg * 4);
      ushort4 h;
      h.x = f2bf(x.x); h.y = f2bf(x.y); h.z = f2bf(x.z); h.w = f2bf(x.w);
      *(ushort4*)(&Xs[xrow * 40 + xseg * 4]) = h;
    }
    __syncthreads();
    s16x8 a0 = *(const s16x8*)(&Xs[l15 * 40 + quad * 8]);
    s16x8 a1 = *(const s16x8*)(&Xs[(16 + l15) * 40 + quad * 8]);
    #pragma unroll
    for (int nt = 0; nt < 8; ++nt) {
      s16x8 bfr = *(const s16x8*)(&Ws[(wave * 128 + nt * 16 + l15) * 40 + quad * 8]);
      acc[0][nt] = __builtin_amdgcn_mfma_f32_16x16x32_bf16(a0, bfr, acc[0][nt], 0, 0, 0);
      acc[1][nt] = __builtin_amdgcn_mfma_f32_16x16x32_bf16(a1, bfr, acc[1][nt], 0, 0, 0);
    }
  }

  // bias add (same col for all 4 rows of a reg)
  #pragma unroll
  for (int nt = 0; nt < 8; ++nt) {
    float bc = bias[wave * 128 + nt * 16 + l15];
    #pragma unroll
    for (int m = 0; m < 2; ++m) {
      acc[m][nt].x += bc; acc[m][nt].y += bc; acc[m][nt].z += bc; acc[m][nt].w += bc;
    }
  }

  // sum of squares per row; wave-partial over its 128 cols
  float s[2][4];
  #pragma unroll
  for (int m = 0; m < 2; ++m)
    #pragma unroll
    for (int r = 0; r < 4; ++r) {
      float t = 0.f;
      #pragma unroll
      for (int nt = 0; nt < 8; ++nt) { float v = acc[m][nt][r]; t += v * v; }
      t += __shfl_xor(t, 1);
      t += __shfl_xor(t, 2);
      t += __shfl_xor(t, 4);
      t += __shfl_xor(t, 8);
      s[m][r] = t;
    }
  if (l15 == 0) {
    #pragma unroll
    for (int m = 0; m < 2; ++m)
      #pragma unroll
      for (int r = 0; r < 4; ++r)
        ssq_lds[wave][m * 16 + quad * 4 + r] = s[m][r];
  }
  __syncthreads();

  // normalize + store bf16
  #pragma unroll
  for (int m = 0; m < 2; ++m) {
    #pragma unroll
    for (int r = 0; r < 4; ++r) {
      int rr = m * 16 + quad * 4 + r;
      float tot = ssq_lds[0][rr] + ssq_lds[1][rr] + ssq_lds[2][rr] + ssq_lds[3][rr];
      float scale = 1.f / fmaxf(sqrtf(tot), 1e-12f);
      long grow = row0 + rr;
      #pragma unroll
      for (int nt = 0; nt < 8; ++nt) {
        int col = wave * 128 + nt * 16 + l15;
        Y[grow * DE + col] = f2bf(acc[m][nt][r] * scale);
      }
    }
  }
}

// ---------------------------------------------------------------------------
// K3: fused similarity + masked max/sum reductions.
// One block per (b,q).  S = v_tok[b] (197x512) @ t_tok[q]^T (512x77).
// M-tiles: 13 (pad 208), N-tiles: 5 (pad 80).  Wave w owns m-tiles w, w+4, ...
// ---------------------------------------------------------------------------
__global__ __launch_bounds__(256, 2) void score_kernel(
    const unsigned short* __restrict__ Yv, const unsigned short* __restrict__ Yt,
    const int* __restrict__ tlen, float* __restrict__ t2v, float* __restrict__ v2t) {
  __shared__ __align__(16) unsigned short As[208 * 72];  // stride 72: 2-way banks
  __shared__ __align__(16) unsigned short Bs[80 * 72];
  __shared__ float colbuf[4][80];
  __shared__ float rowsum_lds[4];

  const int tid = threadIdx.x;
  const int wave = tid >> 6;
  const int lane = tid & 63;
  const int l15 = lane & 15;
  const int quad = lane >> 4;

  // XCD-locality swizzle: idx%8 -> b stays fixed per XCD while q sweeps,
  // keeping v_tok[b] (201 KB) resident in that XCD's L2.
  const int idx = blockIdx.x;
  const int span = idx / 768;          // 0..11
  const int r0 = idx - span * 768;
  const int b = span * 8 + (r0 & 7);
  const int q = r0 >> 3;

  const unsigned short* Ab = Yv + (long)b * (NV * DE);
  const unsigned short* Bb = Yt + (long)q * (NT * DE);

  f32x4 acc[4][5];
  #pragma unroll
  for (int i = 0; i < 4; ++i)
    #pragma unroll
    for (int nt = 0; nt < 5; ++nt)
      acc[i][nt] = (f32x4){0.f, 0.f, 0.f, 0.f};

  for (int kc = 0; kc < DE; kc += 64) {
    __syncthreads();
    // stage A: 208 rows x 64 k  (1664 16B chunks)
    #pragma unroll
    for (int j = 0; j < 7; ++j) {
      int i = tid + j * 256;
      if (i < 1664) {
        int row = i >> 3, seg = i & 7;
        uint4 d = make_uint4(0u, 0u, 0u, 0u);
        if (row < NV) d = *(const uint4*)(Ab + row * DE + kc + seg * 8);
        *(uint4*)(&As[row * 72 + seg * 8]) = d;
      }
    }
    // stage B: 80 rows x 64 k  (640 16B chunks)
    #pragma unroll
    for (int j = 0; j < 3; ++j) {
      int i = tid + j * 256;
      if (i < 640) {
        int row = i >> 3, seg = i & 7;
        uint4 d = make_uint4(0u, 0u, 0u, 0u);
        if (row < NT) d = *(const uint4*)(Bb + row * DE + kc + seg * 8);
        *(uint4*)(&Bs[row * 72 + seg * 8]) = d;
      }
    }
    __syncthreads();
    #pragma unroll
    for (int ks = 0; ks < 64; ks += 32) {
      s16x8 bf[5];
      #pragma unroll
      for (int nt = 0; nt < 5; ++nt)
        bf[nt] = *(const s16x8*)(&Bs[(nt * 16 + l15) * 72 + ks + quad * 8]);
      #pragma unroll
      for (int i = 0; i < 4; ++i) {
        int mt = wave + i * 4;
        if (mt < 13) {
          s16x8 af = *(const s16x8*)(&As[(mt * 16 + l15) * 72 + ks + quad * 8]);
          #pragma unroll
          for (int nt = 0; nt < 5; ++nt)
            acc[i][nt] = __builtin_amdgcn_mfma_f32_16x16x32_bf16(af, bf[nt], acc[i][nt], 0, 0, 0);
        }
      }
    }
  }

  const int len = tlen[q];

  // ---- column max over valid v rows (per col t), t2v path ----
  #pragma unroll
  for (int nt = 0; nt < 5; ++nt) {
    float m = -1e30f;
    #pragma unroll
    for (int i = 0; i < 4; ++i) {
      int mt = wave + i * 4;
      if (mt < 13) {
        int mbase = mt * 16 + quad * 4;
        #pragma unroll
        for (int r = 0; r < 4; ++r)
          if (mbase + r < NV) m = fmaxf(m, acc[i][nt][r]);
      }
    }
    m = fmaxf(m, __shfl_xor(m, 16));
    m = fmaxf(m, __shfl_xor(m, 32));
    if (lane < 16) colbuf[wave][nt * 16 + l15] = m;
  }

  // ---- row max over valid t cols (masked), summed over v, v2t path ----
  float psum = 0.f;
  #pragma unroll
  for (int i = 0; i < 4; ++i) {
    int mt = wave + i * 4;
    if (mt < 13) {
      int mbase = mt * 16 + quad * 4;
      #pragma unroll
      for (int r = 0; r < 4; ++r) {
        float rm = -1e30f;
        #pragma unroll
        for (int nt = 0; nt < 5; ++nt) {
          int c = nt * 16 + l15;
          if (c < len) rm = fmaxf(rm, acc[i][nt][r]);
        }
        rm = fmaxf(rm, __shfl_xor(rm, 1));
        rm = fmaxf(rm, __shfl_xor(rm, 2));
        rm = fmaxf(rm, __shfl_xor(rm, 4));
        rm = fmaxf(rm, __shfl_xor(rm, 8));
        // masked logits are 0 at t in [len, 77); max includes them iff len < 77
        if (len < NT) rm = fmaxf(rm, 0.f);
        if (l15 == 0 && (mbase + r) < NV) psum += rm;
      }
    }
  }
  psum += __shfl_xor(psum, 1);
  psum += __shfl_xor(psum, 2);
  psum += __shfl_xor(psum, 4);
  psum += __shfl_xor(psum, 8);
  psum += __shfl_xor(psum, 16);
  psum += __shfl_xor(psum, 32);
  if (lane == 0) rowsum_lds[wave] = psum;
  __syncthreads();

  if (wave == 0) {
    float ssum = 0.f;
    for (int c = lane; c < 80; c += 64) {
      if (c < len) {
        float m = fmaxf(fmaxf(colbuf[0][c], colbuf[1][c]),
                        fmaxf(colbuf[2][c], colbuf[3][c]));
        ssum += m;
      }
    }
    ssum += __shfl_xor(ssum, 1);
    ssum += __shfl_xor(ssum, 2);
    ssum += __shfl_xor(ssum, 4);
    ssum += __shfl_xor(ssum, 8);
    ssum += __shfl_xor(ssum, 16);
    ssum += __shfl_xor(ssum, 32);
    if (lane == 0) {
      t2v[b * NQ + q] = ssum / (float)len;
      v2t[b * NQ + q] = (rowsum_lds[0] + rowsum_lds[1] + rowsum_lds[2] + rowsum_lds[3]) / (float)NV;
    }
  }
}

// ---------------------------------------------------------------------------
extern "C" void kernel_launch(void* const* d_in, const int* in_sizes, int n_in,
                              void* d_out, int out_size, void* d_ws, size_t ws_size,
                              hipStream_t stream) {
  (void)in_sizes; (void)n_in; (void)out_size; (void)ws_size;
  const float* visual_cls     = (const float*)d_in[0];
  const float* visual_tokens  = (const float*)d_in[1];
  const float* textual_cls    = (const float*)d_in[2];
  const float* textual_tokens = (const float*)d_in[3];
  const float* Wv_cls = (const float*)d_in[4];
  const float* bv_cls = (const float*)d_in[5];
  const float* Wt_cls = (const float*)d_in[6];
  const float* bt_cls = (const float*)d_in[7];
  const float* Wv_tok = (const float*)d_in[8];
  const float* bv_tok = (const float*)d_in[9];
  const float* Wt_tok = (const float*)d_in[10];
  const float* bt_tok = (const float*)d_in[11];
  const int* text_length = (const int*)d_in[12];

  float* out = (float*)d_out;
  float* v_cls_o = out;                       // 96*512
  float* t_cls_o = out + 49152;               // 96*512
  float* t2v_o   = out + 98304;               // 96*96
  float* v2t_o   = out + 107520;              // 96*96

  char* ws = (char*)d_ws;
  unsigned short* Wvb = (unsigned short*)(ws);                 // 512*768*2 = 786432 B
  unsigned short* Wtb = (unsigned short*)(ws + 786432);        // 786432 B
  unsigned short* Yv  = (unsigned short*)(ws + 1572864);       // 18912*512*2 = 19365888 B
  unsigned short* Yt  = (unsigned short*)(ws + 20938752);      // 7392*512*2  = 7569408 B
                                                               // total 28508160 B

  cvt_bf16_kernel<<<384, 256, 0, stream>>>(Wv_tok, Wvb, 98304);
  cvt_bf16_kernel<<<384, 256, 0, stream>>>(Wt_tok, Wtb, 98304);

  cls_kernel<<<NB, 256, 0, stream>>>(visual_cls, Wv_cls, bv_cls, v_cls_o);
  cls_kernel<<<NQ, 256, 0, stream>>>(textual_cls, Wt_cls, bt_cls, t_cls_o);

  proj_norm_kernel<<<(NB * NV) / 32, 256, 0, stream>>>(visual_tokens, Wvb, bv_tok, Yv);
  proj_norm_kernel<<<(NQ * NT) / 32, 256, 0, stream>>>(textual_tokens, Wtb, bt_tok, Yt);

  score_kernel<<<NB * NQ, 256, 0, stream>>>(Yv, Yt, text_length, t2v_o, v2t_o);
}

// Round 2
// 561.890 us; speedup vs baseline: 1.2221x; 1.2221x over previous
//
#include <hip/hip_runtime.h>

// Problem constants
#define NB 96
#define NQ 96
#define NV 197
#define NT 77
#define DK 768
#define DE 512

typedef __attribute__((ext_vector_type(8))) short s16x8;
typedef __attribute__((ext_vector_type(4))) float f32x4;

__device__ __forceinline__ unsigned short f2bf(float f) {
  union { float f; unsigned int u; } v; v.f = f;
  unsigned int u = v.u;
  unsigned int r = u + 0x7fffu + ((u >> 16) & 1u);
  return (unsigned short)(r >> 16);
}

#define GLOAD_LDS16(gp, lp)                                              \
  __builtin_amdgcn_global_load_lds(                                      \
      (const __attribute__((address_space(1))) void*)(gp),               \
      (__attribute__((address_space(3))) void*)(lp), 16, 0, 0)

// ---------------------------------------------------------------------------
// K0: fp32 -> bf16 conversion (for weight matrices)
// ---------------------------------------------------------------------------
__global__ __launch_bounds__(256) void cvt_bf16_kernel(
    const float* __restrict__ src, unsigned short* __restrict__ dst, int n4) {
  int i = blockIdx.x * 256 + threadIdx.x;
  if (i < n4) {
    float4 x = ((const float4*)src)[i];
    ushort4 h;
    h.x = f2bf(x.x); h.y = f2bf(x.y); h.z = f2bf(x.z); h.w = f2bf(x.w);
    ((ushort4*)dst)[i] = h;
  }
}

// ---------------------------------------------------------------------------
// K1: cls projection, fp32 exact.  One block per output row.
// ---------------------------------------------------------------------------
__global__ __launch_bounds__(256) void cls_kernel(
    const float* __restrict__ X, const float* __restrict__ W,
    const float* __restrict__ bias, float* __restrict__ out) {
  __shared__ float xs[DK];
  const int row = blockIdx.x;
  const float* xr = X + (long)row * DK;
  for (int i = threadIdx.x; i < DK; i += 256) xs[i] = xr[i];
  __syncthreads();
  for (int c = threadIdx.x; c < DE; c += 256) {
    const float* wr = W + (long)c * DK;
    float s = 0.f;
    #pragma unroll 4
    for (int k = 0; k < DK; k += 4) {
      float4 w4 = *(const float4*)(wr + k);
      s += xs[k] * w4.x + xs[k + 1] * w4.y + xs[k + 2] * w4.z + xs[k + 3] * w4.w;
    }
    out[(long)row * DE + c] = s + bias[c];
  }
}

// ---------------------------------------------------------------------------
// K2: token projection + bias + l2norm, MFMA bf16.  (unchanged this round)
// ---------------------------------------------------------------------------
__global__ __launch_bounds__(256, 2) void proj_norm_kernel(
    const float* __restrict__ X, const unsigned short* __restrict__ Wb,
    const float* __restrict__ bias, unsigned short* __restrict__ Y) {
  __shared__ __align__(16) unsigned short Ws[512 * 40];
  __shared__ __align__(16) unsigned short Xs[32 * 40];
  __shared__ float ssq_lds[4][32];

  const int tid = threadIdx.x;
  const int wave = tid >> 6;
  const int lane = tid & 63;
  const int l15 = lane & 15;
  const int quad = lane >> 4;
  const long row0 = (long)blockIdx.x * 32;

  f32x4 acc[2][8];
  #pragma unroll
  for (int m = 0; m < 2; ++m)
    #pragma unroll
    for (int n = 0; n < 8; ++n)
      acc[m][n] = (f32x4){0.f, 0.f, 0.f, 0.f};

  const int xrow = tid >> 3;
  const int xseg = tid & 7;

  for (int kc = 0; kc < DK; kc += 32) {
    __syncthreads();
    #pragma unroll
    for (int j = 0; j < 8; ++j) {
      int i = tid + j * 256;
      int col = i >> 2, seg = i & 3;
      uint4 d = *(const uint4*)(Wb + (long)col * DK + kc + seg * 8);
      *(uint4*)(&Ws[col * 40 + seg * 8]) = d;
    }
    {
      float4 x = *(const float4*)(X + (row0 + xrow) * DK + kc + xseg * 4);
      ushort4 h;
      h.x = f2bf(x.x); h.y = f2bf(x.y); h.z = f2bf(x.z); h.w = f2bf(x.w);
      *(ushort4*)(&Xs[xrow * 40 + xseg * 4]) = h;
    }
    __syncthreads();
    s16x8 a0 = *(const s16x8*)(&Xs[l15 * 40 + quad * 8]);
    s16x8 a1 = *(const s16x8*)(&Xs[(16 + l15) * 40 + quad * 8]);
    #pragma unroll
    for (int nt = 0; nt < 8; ++nt) {
      s16x8 bfr = *(const s16x8*)(&Ws[(wave * 128 + nt * 16 + l15) * 40 + quad * 8]);
      acc[0][nt] = __builtin_amdgcn_mfma_f32_16x16x32_bf16(a0, bfr, acc[0][nt], 0, 0, 0);
      acc[1][nt] = __builtin_amdgcn_mfma_f32_16x16x32_bf16(a1, bfr, acc[1][nt], 0, 0, 0);
    }
  }

  #pragma unroll
  for (int nt = 0; nt < 8; ++nt) {
    float bc = bias[wave * 128 + nt * 16 + l15];
    #pragma unroll
    for (int m = 0; m < 2; ++m) {
      acc[m][nt].x += bc; acc[m][nt].y += bc; acc[m][nt].z += bc; acc[m][nt].w += bc;
    }
  }

  float s[2][4];
  #pragma unroll
  for (int m = 0; m < 2; ++m)
    #pragma unroll
    for (int r = 0; r < 4; ++r) {
      float t = 0.f;
      #pragma unroll
      for (int nt = 0; nt < 8; ++nt) { float v = acc[m][nt][r]; t += v * v; }
      t += __shfl_xor(t, 1);
      t += __shfl_xor(t, 2);
      t += __shfl_xor(t, 4);
      t += __shfl_xor(t, 8);
      s[m][r] = t;
    }
  if (l15 == 0) {
    #pragma unroll
    for (int m = 0; m < 2; ++m)
      #pragma unroll
      for (int r = 0; r < 4; ++r)
        ssq_lds[wave][m * 16 + quad * 4 + r] = s[m][r];
  }
  __syncthreads();

  #pragma unroll
  for (int m = 0; m < 2; ++m) {
    #pragma unroll
    for (int r = 0; r < 4; ++r) {
      int rr = m * 16 + quad * 4 + r;
      float tot = ssq_lds[0][rr] + ssq_lds[1][rr] + ssq_lds[2][rr] + ssq_lds[3][rr];
      float scale = 1.f / fmaxf(sqrtf(tot), 1e-12f);
      long grow = row0 + rr;
      #pragma unroll
      for (int nt = 0; nt < 8; ++nt) {
        int col = wave * 128 + nt * 16 + l15;
        Y[grow * DE + col] = f2bf(acc[m][nt][r] * scale);
      }
    }
  }
}

// ---------------------------------------------------------------------------
// K3: fused similarity + masked max/sum reductions.
// One block per (b, q-pair).  QB=2: B tile = 160 rows (2 x 80), 10 n-tiles.
// A staged via global_load_lds (16B), unpadded stride 64 elts, XOR swizzle
// on the global fetch side (seg ^ row&7) so ds_read frags are 2-way/bank.
// ---------------------------------------------------------------------------
__global__ __launch_bounds__(256, 2) void score_kernel(
    const unsigned short* __restrict__ Yv, const unsigned short* __restrict__ Yt,
    const int* __restrict__ tlen, float* __restrict__ t2v, float* __restrict__ v2t) {
  __shared__ __align__(16) unsigned short As[208 * 64];   // 26,624 B
  __shared__ __align__(16) unsigned short Bs[160 * 64];   // 20,480 B
  __shared__ float colbuf[4][160];
  __shared__ float rowsum_lds[4][2];

  const int tid = threadIdx.x;
  const int wave = tid >> 6;
  const int lane = tid & 63;
  const int l15 = lane & 15;
  const int quad = lane >> 4;

  // XCD-locality swizzle: b fixed per XCD while qi sweeps.
  const int idx = blockIdx.x;
  const int span = idx / 384;          // 0..11
  const int r0 = idx - span * 384;
  const int b = span * 8 + (r0 & 7);
  const int qi = r0 >> 3;              // 0..47
  const int q0 = qi * 2;

  const unsigned short* Ab = Yv + (long)b * (NV * DE);
  const unsigned short* Bb = Yt + (long)q0 * (NT * DE);

  f32x4 acc[4][10];
  #pragma unroll
  for (int i = 0; i < 4; ++i)
    #pragma unroll
    for (int nt = 0; nt < 10; ++nt)
      acc[i][nt] = (f32x4){0.f, 0.f, 0.f, 0.f};

  for (int kc = 0; kc < DE; kc += 64) {
    __syncthreads();
    // stage A: 26 segments of 1 KB (8 rows x 64 k each), row-clamped
    for (int s = wave; s < 26; s += 4) {
      int i = (s << 6) + lane;
      int row = i >> 3, seg = i & 7;
      int grow = row < NV ? row : (NV - 1);
      const unsigned short* gp = Ab + grow * DE + kc + ((seg ^ (row & 7)) << 3);
      GLOAD_LDS16(gp, &As[s << 9]);
    }
    // stage B: 20 segments; rows 0..79 = q0 (t clamped to 76), 80..159 = q1
    for (int s = wave; s < 20; s += 4) {
      int i = (s << 6) + lane;
      int r = i >> 3, seg = i & 7;
      int half = (r >= 80) ? 1 : 0;
      int t = r - 80 * half;
      t = t < NT ? t : (NT - 1);
      const unsigned short* gp = Bb + (long)half * (NT * DE) + t * DE + kc + ((seg ^ (r & 7)) << 3);
      GLOAD_LDS16(gp, &Bs[s << 9]);
    }
    __syncthreads();   // drains vmcnt for the global_load_lds queue
    #pragma unroll
    for (int ks = 0; ks < 2; ++ks) {
      const int segbase = ks << 2;  // 0 or 4
      s16x8 bf[10];
      #pragma unroll
      for (int nt = 0; nt < 10; ++nt) {
        int brow = nt * 16 + l15;
        bf[nt] = *(const s16x8*)&Bs[(brow << 6) + (((segbase + quad) ^ (brow & 7)) << 3)];
      }
      #pragma unroll
      for (int i = 0; i < 4; ++i) {
        int mt = wave + (i << 2);
        if (mt < 13) {
          int arow = mt * 16 + l15;
          s16x8 af = *(const s16x8*)&As[(arow << 6) + (((segbase + quad) ^ (arow & 7)) << 3)];
          #pragma unroll
          for (int nt = 0; nt < 10; ++nt)
            acc[i][nt] = __builtin_amdgcn_mfma_f32_16x16x32_bf16(af, bf[nt], acc[i][nt], 0, 0, 0);
        }
      }
    }
  }

  const int len0 = tlen[q0];
  const int len1 = tlen[q0 + 1];

  // ---- column max over valid v rows (t2v path), both q halves ----
  #pragma unroll
  for (int nt = 0; nt < 10; ++nt) {
    float m = -1e30f;
    #pragma unroll
    for (int i = 0; i < 4; ++i) {
      int mt = wave + (i << 2);
      if (mt < 13) {
        int mbase = mt * 16 + quad * 4;
        #pragma unroll
        for (int r = 0; r < 4; ++r)
          if (mbase + r < NV) m = fmaxf(m, acc[i][nt][r]);
      }
    }
    m = fmaxf(m, __shfl_xor(m, 16));
    m = fmaxf(m, __shfl_xor(m, 32));
    if (lane < 16) colbuf[wave][nt * 16 + l15] = m;
  }

  // ---- row max over valid t cols (v2t path), per q half ----
  float psum[2] = {0.f, 0.f};
  #pragma unroll
  for (int h = 0; h < 2; ++h) {
    int len = h ? len1 : len0;
    #pragma unroll
    for (int i = 0; i < 4; ++i) {
      int mt = wave + (i << 2);
      if (mt < 13) {
        int mbase = mt * 16 + quad * 4;
        #pragma unroll
        for (int r = 0; r < 4; ++r) {
          float rm = -1e30f;
          #pragma unroll
          for (int nt = 0; nt < 5; ++nt) {
            int c = nt * 16 + l15;
            if (c < len) rm = fmaxf(rm, acc[i][h * 5 + nt][r]);
          }
          rm = fmaxf(rm, __shfl_xor(rm, 1));
          rm = fmaxf(rm, __shfl_xor(rm, 2));
          rm = fmaxf(rm, __shfl_xor(rm, 4));
          rm = fmaxf(rm, __shfl_xor(rm, 8));
          if (len < NT) rm = fmaxf(rm, 0.f);  // masked zeros participate in max
          if (l15 == 0 && (mbase + r) < NV) psum[h] += rm;
        }
      }
    }
    psum[h] += __shfl_xor(psum[h], 16);
    psum[h] += __shfl_xor(psum[h], 32);
  }
  if (lane == 0) { rowsum_lds[wave][0] = psum[0]; rowsum_lds[wave][1] = psum[1]; }
  __syncthreads();

  if (wave < 2) {
    int q = q0 + wave;
    int len = wave ? len1 : len0;
    int cbase = wave * 80;
    float ssum = 0.f;
    for (int c = lane; c < 80; c += 64) {
      if (c < len) {
        float m = fmaxf(fmaxf(colbuf[0][cbase + c], colbuf[1][cbase + c]),
                        fmaxf(colbuf[2][cbase + c], colbuf[3][cbase + c]));
        ssum += m;
      }
    }
    ssum += __shfl_xor(ssum, 1);
    ssum += __shfl_xor(ssum, 2);
    ssum += __shfl_xor(ssum, 4);
    ssum += __shfl_xor(ssum, 8);
    ssum += __shfl_xor(ssum, 16);
    ssum += __shfl_xor(ssum, 32);
    if (lane == 0) {
      float rs = rowsum_lds[0][wave] + rowsum_lds[1][wave] +
                 rowsum_lds[2][wave] + rowsum_lds[3][wave];
      t2v[b * NQ + q] = ssum / (float)len;
      v2t[b * NQ + q] = rs / (float)NV;
    }
  }
}

// ---------------------------------------------------------------------------
extern "C" void kernel_launch(void* const* d_in, const int* in_sizes, int n_in,
                              void* d_out, int out_size, void* d_ws, size_t ws_size,
                              hipStream_t stream) {
  (void)in_sizes; (void)n_in; (void)out_size; (void)ws_size;
  const float* visual_cls     = (const float*)d_in[0];
  const float* visual_tokens  = (const float*)d_in[1];
  const float* textual_cls    = (const float*)d_in[2];
  const float* textual_tokens = (const float*)d_in[3];
  const float* Wv_cls = (const float*)d_in[4];
  const float* bv_cls = (const float*)d_in[5];
  const float* Wt_cls = (const float*)d_in[6];
  const float* bt_cls = (const float*)d_in[7];
  const float* Wv_tok = (const float*)d_in[8];
  const float* bv_tok = (const float*)d_in[9];
  const float* Wt_tok = (const float*)d_in[10];
  const float* bt_tok = (const float*)d_in[11];
  const int* text_length = (const int*)d_in[12];

  float* out = (float*)d_out;
  float* v_cls_o = out;
  float* t_cls_o = out + 49152;
  float* t2v_o   = out + 98304;
  float* v2t_o   = out + 107520;

  char* ws = (char*)d_ws;
  unsigned short* Wvb = (unsigned short*)(ws);
  unsigned short* Wtb = (unsigned short*)(ws + 786432);
  unsigned short* Yv  = (unsigned short*)(ws + 1572864);
  unsigned short* Yt  = (unsigned short*)(ws + 20938752);

  cvt_bf16_kernel<<<384, 256, 0, stream>>>(Wv_tok, Wvb, 98304);
  cvt_bf16_kernel<<<384, 256, 0, stream>>>(Wt_tok, Wtb, 98304);

  cls_kernel<<<NB, 256, 0, stream>>>(visual_cls, Wv_cls, bv_cls, v_cls_o);
  cls_kernel<<<NQ, 256, 0, stream>>>(textual_cls, Wt_cls, bt_cls, t_cls_o);

  proj_norm_kernel<<<(NB * NV) / 32, 256, 0, stream>>>(visual_tokens, Wvb, bv_tok, Yv);
  proj_norm_kernel<<<(NQ * NT) / 32, 256, 0, stream>>>(textual_tokens, Wtb, bt_tok, Yt);

  score_kernel<<<(NB * NQ) / 2, 256, 0, stream>>>(Yv, Yt, text_length, t2v_o, v2t_o);
}

// Round 3
// 494.030 us; speedup vs baseline: 1.3900x; 1.1374x over previous
//
#include <hip/hip_runtime.h>

// Problem constants
#define NB 96
#define NQ 96
#define NV 197
#define NT 77
#define DK 768
#define DE 512

typedef __attribute__((ext_vector_type(8))) short s16x8;
typedef __attribute__((ext_vector_type(4))) float f32x4;

__device__ __forceinline__ unsigned short f2bf(float f) {
  union { float f; unsigned int u; } v; v.f = f;
  unsigned int u = v.u;
  unsigned int r = u + 0x7fffu + ((u >> 16) & 1u);
  return (unsigned short)(r >> 16);
}

__device__ __forceinline__ unsigned int pack2bf(float a, float b) {
  return (unsigned int)f2bf(a) | ((unsigned int)f2bf(b) << 16);
}

// global -> LDS direct, 16B/lane.  gp is per-lane; LDS dest = uniform base +
// lane*16.  off must be a compile-time constant (13-bit signed, bytes).
#define GL16(gp, lp, off)                                                \
  __builtin_amdgcn_global_load_lds(                                      \
      (const __attribute__((address_space(1))) void*)(gp),               \
      (__attribute__((address_space(3))) void*)(lp), 16, (off), 0)

// ---------------------------------------------------------------------------
// K0: fp32 -> bf16 conversion (for weight matrices)
// ---------------------------------------------------------------------------
__global__ __launch_bounds__(256) void cvt_bf16_kernel(
    const float* __restrict__ src, unsigned short* __restrict__ dst, int n4) {
  int i = blockIdx.x * 256 + threadIdx.x;
  if (i < n4) {
    float4 x = ((const float4*)src)[i];
    ushort4 h;
    h.x = f2bf(x.x); h.y = f2bf(x.y); h.z = f2bf(x.z); h.w = f2bf(x.w);
    ((ushort4*)dst)[i] = h;
  }
}

// ---------------------------------------------------------------------------
// K1: cls projection, fp32 exact.  One block per output row.
// ---------------------------------------------------------------------------
__global__ __launch_bounds__(256) void cls_kernel(
    const float* __restrict__ X, const float* __restrict__ W,
    const float* __restrict__ bias, float* __restrict__ out) {
  __shared__ float xs[DK];
  const int row = blockIdx.x;
  const float* xr = X + (long)row * DK;
  for (int i = threadIdx.x; i < DK; i += 256) xs[i] = xr[i];
  __syncthreads();
  for (int c = threadIdx.x; c < DE; c += 256) {
    const float* wr = W + (long)c * DK;
    float s = 0.f;
    #pragma unroll 4
    for (int k = 0; k < DK; k += 4) {
      float4 w4 = *(const float4*)(wr + k);
      s += xs[k] * w4.x + xs[k + 1] * w4.y + xs[k + 2] * w4.z + xs[k + 3] * w4.w;
    }
    out[(long)row * DE + c] = s + bias[c];
  }
}

// ---------------------------------------------------------------------------
// K2: token projection + bias + l2norm, MFMA bf16.  REWRITTEN:
// Block = 64 rows x 512 cols.  K-chunk 64, 12 iters.
// W staged via global_load_lds 16B (walking pointer, stride 32*DK/seg);
// X staged fp32->bf16 via ds_write_b128.  XOR-swizzled unpadded LDS.
// Wave w owns cols [w*128, w*128+128) as 8 n-tiles; 4 m-tiles of 16 rows.
// ---------------------------------------------------------------------------
__global__ __launch_bounds__(256, 2) void proj_norm_kernel(
    const float* __restrict__ X, const unsigned short* __restrict__ Wb,
    const float* __restrict__ bias, unsigned short* __restrict__ Y, int M) {
  __shared__ __align__(16) unsigned short Ws[512 * 64];  // 65536 B
  __shared__ __align__(16) unsigned short Xs[64 * 64];   // 8192 B
  __shared__ float ssq_lds[4][64];

  const int tid = threadIdx.x;
  const int wave = tid >> 6;
  const int lane = tid & 63;
  const int l15 = lane & 15;
  const int quad = lane >> 4;
  const long row0 = (long)blockIdx.x * 64;

  // ---- staging pointers (k-invariant bases) ----
  const int sub = lane >> 3;                 // 0..7
  const int swz = ((lane & 7) ^ sub) << 3;   // element offset
  // W: seg s = j*4+wave, row = s*8+sub; walking pointer, stride 32*DK elems
  const unsigned short* pw_base = Wb + (long)(wave * 8 + sub) * DK + swz;

  // X: thread handles granules g = tid and tid+256 of the 64x64 tile
  const int xrow_a = tid >> 3;               // 0..31
  const int xrow_b = xrow_a + 32;            // 32..63
  const int xs8 = tid & 7;
  long gra = row0 + xrow_a; if (gra > M - 1) gra = M - 1;
  long grb = row0 + xrow_b; if (grb > M - 1) grb = M - 1;
  const float* px_a = X + gra * DK + xs8 * 8;
  const float* px_b = X + grb * DK + xs8 * 8;
  const int xaddr_a = (xrow_a << 6) + ((xs8 ^ (xrow_a & 7)) << 3);
  const int xaddr_b = (xrow_b << 6) + ((xs8 ^ (xrow_b & 7)) << 3);

  f32x4 acc[4][8];
  #pragma unroll
  for (int m = 0; m < 4; ++m)
    #pragma unroll
    for (int n = 0; n < 8; ++n)
      acc[m][n] = (f32x4){0.f, 0.f, 0.f, 0.f};

  for (int kc = 0; kc < DK; kc += 64) {
    __syncthreads();
    // stage X (fp32 -> bf16, swizzled ds_write_b128)
    {
      float4 x0 = *(const float4*)(px_a);
      float4 x1 = *(const float4*)(px_a + 4);
      uint4 h;
      h.x = pack2bf(x0.x, x0.y); h.y = pack2bf(x0.z, x0.w);
      h.z = pack2bf(x1.x, x1.y); h.w = pack2bf(x1.z, x1.w);
      *(uint4*)(&Xs[xaddr_a]) = h;
      x0 = *(const float4*)(px_b);
      x1 = *(const float4*)(px_b + 4);
      h.x = pack2bf(x0.x, x0.y); h.y = pack2bf(x0.z, x0.w);
      h.z = pack2bf(x1.x, x1.y); h.w = pack2bf(x1.z, x1.w);
      *(uint4*)(&Xs[xaddr_b]) = h;
      px_a += 64; px_b += 64;
    }
    // stage W (global_load_lds, walking pointer)
    {
      const unsigned short* pw = pw_base;
      #pragma unroll
      for (int j = 0; j < 16; ++j) {
        GL16(pw, &Ws[(j * 4 + wave) << 9], 0);
        pw += 32 * DK;
      }
      pw_base += 64;
    }
    __syncthreads();
    #pragma unroll
    for (int ks = 0; ks < 2; ++ks) {
      s16x8 af[4];
      #pragma unroll
      for (int mi = 0; mi < 4; ++mi) {
        int arow = mi * 16 + l15;
        af[mi] = *(const s16x8*)&Xs[(arow << 6) + ((((ks << 2) + quad) ^ (arow & 7)) << 3)];
      }
      #pragma unroll
      for (int nt = 0; nt < 8; ++nt) {
        int wrow = wave * 128 + nt * 16 + l15;
        s16x8 bfr = *(const s16x8*)&Ws[(wrow << 6) + ((((ks << 2) + quad) ^ (wrow & 7)) << 3)];
        #pragma unroll
        for (int mi = 0; mi < 4; ++mi)
          acc[mi][nt] = __builtin_amdgcn_mfma_f32_16x16x32_bf16(af[mi], bfr, acc[mi][nt], 0, 0, 0);
      }
    }
  }

  // bias add
  #pragma unroll
  for (int nt = 0; nt < 8; ++nt) {
    float bc = bias[wave * 128 + nt * 16 + l15];
    #pragma unroll
    for (int mi = 0; mi < 4; ++mi) {
      acc[mi][nt].x += bc; acc[mi][nt].y += bc; acc[mi][nt].z += bc; acc[mi][nt].w += bc;
    }
  }

  // sum of squares per row; wave covers 128 cols -> reduce over l15
  #pragma unroll
  for (int mi = 0; mi < 4; ++mi)
    #pragma unroll
    for (int r = 0; r < 4; ++r) {
      float t = 0.f;
      #pragma unroll
      for (int nt = 0; nt < 8; ++nt) { float v = acc[mi][nt][r]; t += v * v; }
      t += __shfl_xor(t, 1);
      t += __shfl_xor(t, 2);
      t += __shfl_xor(t, 4);
      t += __shfl_xor(t, 8);
      if (l15 == 0) ssq_lds[wave][mi * 16 + quad * 4 + r] = t;
    }
  __syncthreads();

  // normalize + store bf16
  #pragma unroll
  for (int mi = 0; mi < 4; ++mi) {
    #pragma unroll
    for (int r = 0; r < 4; ++r) {
      int rr = mi * 16 + quad * 4 + r;
      float tot = ssq_lds[0][rr] + ssq_lds[1][rr] + ssq_lds[2][rr] + ssq_lds[3][rr];
      float scale = 1.f / fmaxf(sqrtf(tot), 1e-12f);
      long grow = row0 + rr;
      if (grow < M) {
        #pragma unroll
        for (int nt = 0; nt < 8; ++nt) {
          int col = wave * 128 + nt * 16 + l15;
          Y[grow * DE + col] = f2bf(acc[mi][nt][r] * scale);
        }
      }
    }
  }
}

// ---------------------------------------------------------------------------
// K3: fused similarity + masked max/sum reductions.
// One block per (b, q-pair).  All staging addresses hoisted: per-thread
// global base pointers precomputed; K advance via the builtin's immediate
// offset (K-loop fully unrolled, 8 iters x 128 B).
// ---------------------------------------------------------------------------
__global__ __launch_bounds__(256, 2) void score_kernel(
    const unsigned short* __restrict__ Yv, const unsigned short* __restrict__ Yt,
    const int* __restrict__ tlen, float* __restrict__ t2v, float* __restrict__ v2t) {
  __shared__ __align__(16) unsigned short As[208 * 64];   // 26,624 B
  __shared__ __align__(16) unsigned short Bs[160 * 64];   // 20,480 B
  __shared__ float colbuf[4][160];
  __shared__ float rowsum_lds[4][2];

  const int tid = threadIdx.x;
  const int wave = tid >> 6;
  const int lane = tid & 63;
  const int l15 = lane & 15;
  const int quad = lane >> 4;

  // XCD-locality swizzle: b fixed per XCD while qi sweeps.
  const int idx = blockIdx.x;
  const int span = idx / 384;          // 0..11
  const int r0 = idx - span * 384;
  const int b = span * 8 + (r0 & 7);
  const int qi = r0 >> 3;              // 0..47
  const int q0 = qi * 2;

  const unsigned short* Ab = Yv + (long)b * (NV * DE);
  const unsigned short* Bb = Yt + (long)q0 * (NT * DE);

  // ---- k-invariant staging pointers ----
  const int sub = lane >> 3;                 // 0..7
  const int swz = ((lane & 7) ^ sub) << 3;
  const unsigned short* pA[7];
  #pragma unroll
  for (int j = 0; j < 6; ++j) {
    int row = (j * 4 + wave) * 8 + sub;      // 0..191, no clamp needed
    pA[j] = Ab + row * DE + swz;
  }
  {
    int row = (24 + (wave & 1)) * 8 + sub;   // 192..207 (waves 2,3 use it)
    if (row > NV - 1) row = NV - 1;
    pA[6] = Ab + row * DE + swz;
  }
  const unsigned short* pB[5];
  #pragma unroll
  for (int j = 0; j < 5; ++j) {
    int r = (j * 4 + wave) * 8 + sub;        // 0..159
    int half = (r >= 80) ? 1 : 0;
    int t = r - 80 * half;
    if (t > NT - 1) t = NT - 1;
    pB[j] = Bb + (long)half * (NT * DE) + t * DE + swz;
  }

  // ---- k-invariant LDS fragment offsets (elements) ----
  int aoff[4][2], boff[10][2];
  #pragma unroll
  for (int i = 0; i < 4; ++i) {
    int arow = (wave + i * 4) * 16 + l15;
    #pragma unroll
    for (int ks = 0; ks < 2; ++ks)
      aoff[i][ks] = (arow << 6) + ((((ks << 2) + quad) ^ (arow & 7)) << 3);
  }
  #pragma unroll
  for (int nt = 0; nt < 10; ++nt) {
    int brow = nt * 16 + l15;
    #pragma unroll
    for (int ks = 0; ks < 2; ++ks)
      boff[nt][ks] = (brow << 6) + ((((ks << 2) + quad) ^ (brow & 7)) << 3);
  }

  f32x4 acc[4][10];
  #pragma unroll
  for (int i = 0; i < 4; ++i)
    #pragma unroll
    for (int nt = 0; nt < 10; ++nt)
      acc[i][nt] = (f32x4){0.f, 0.f, 0.f, 0.f};

  auto do_compute = [&]() {
    #pragma unroll
    for (int ks = 0; ks < 2; ++ks) {
      s16x8 bf[10];
      #pragma unroll
      for (int nt = 0; nt < 10; ++nt)
        bf[nt] = *(const s16x8*)&Bs[boff[nt][ks]];
      #pragma unroll
      for (int i = 0; i < 4; ++i) {
        int mt = wave + (i << 2);
        if (mt < 13) {
          s16x8 af = *(const s16x8*)&As[aoff[i][ks]];
          #pragma unroll
          for (int nt = 0; nt < 10; ++nt)
            acc[i][nt] = __builtin_amdgcn_mfma_f32_16x16x32_bf16(af, bf[nt], acc[i][nt], 0, 0, 0);
        }
      }
    }
  };

#define SCORE_STAGE(KB)                                                  \
  {                                                                      \
    _Pragma("unroll")                                                    \
    for (int j = 0; j < 6; ++j)                                          \
      GL16(pA[j], &As[(j * 4 + wave) << 9], KB);                         \
    if (wave >= 2)                                                       \
      GL16(pA[6], &As[(24 + (wave & 1)) << 9], KB);                      \
    _Pragma("unroll")                                                    \
    for (int j = 0; j < 5; ++j)                                          \
      GL16(pB[j], &Bs[(j * 4 + wave) << 9], KB);                         \
  }

#define SCORE_ITER(KB) { __syncthreads(); SCORE_STAGE(KB); __syncthreads(); do_compute(); }

  SCORE_ITER(0)
  SCORE_ITER(128)
  SCORE_ITER(256)
  SCORE_ITER(384)
  SCORE_ITER(512)
  SCORE_ITER(640)
  SCORE_ITER(768)
  SCORE_ITER(896)

#undef SCORE_ITER
#undef SCORE_STAGE

  const int len0 = tlen[q0];
  const int len1 = tlen[q0 + 1];

  // ---- column max over valid v rows (t2v path), both q halves ----
  #pragma unroll
  for (int nt = 0; nt < 10; ++nt) {
    float m = -1e30f;
    #pragma unroll
    for (int i = 0; i < 4; ++i) {
      int mt = wave + (i << 2);
      if (mt < 13) {
        int mbase = mt * 16 + quad * 4;
        #pragma unroll
        for (int r = 0; r < 4; ++r)
          if (mbase + r < NV) m = fmaxf(m, acc[i][nt][r]);
      }
    }
    m = fmaxf(m, __shfl_xor(m, 16));
    m = fmaxf(m, __shfl_xor(m, 32));
    if (lane < 16) colbuf[wave][nt * 16 + l15] = m;
  }

  // ---- row max over valid t cols (v2t path), per q half ----
  float psum[2] = {0.f, 0.f};
  #pragma unroll
  for (int h = 0; h < 2; ++h) {
    int len = h ? len1 : len0;
    #pragma unroll
    for (int i = 0; i < 4; ++i) {
      int mt = wave + (i << 2);
      if (mt < 13) {
        int mbase = mt * 16 + quad * 4;
        #pragma unroll
        for (int r = 0; r < 4; ++r) {
          float rm = -1e30f;
          #pragma unroll
          for (int nt = 0; nt < 5; ++nt) {
            int c = nt * 16 + l15;
            if (c < len) rm = fmaxf(rm, acc[i][h * 5 + nt][r]);
          }
          rm = fmaxf(rm, __shfl_xor(rm, 1));
          rm = fmaxf(rm, __shfl_xor(rm, 2));
          rm = fmaxf(rm, __shfl_xor(rm, 4));
          rm = fmaxf(rm, __shfl_xor(rm, 8));
          if (len < NT) rm = fmaxf(rm, 0.f);  // masked zeros participate in max
          if (l15 == 0 && (mbase + r) < NV) psum[h] += rm;
        }
      }
    }
    psum[h] += __shfl_xor(psum[h], 16);
    psum[h] += __shfl_xor(psum[h], 32);
  }
  if (lane == 0) { rowsum_lds[wave][0] = psum[0]; rowsum_lds[wave][1] = psum[1]; }
  __syncthreads();

  if (wave < 2) {
    int q = q0 + wave;
    int len = wave ? len1 : len0;
    int cbase = wave * 80;
    float ssum = 0.f;
    for (int c = lane; c < 80; c += 64) {
      if (c < len) {
        float m = fmaxf(fmaxf(colbuf[0][cbase + c], colbuf[1][cbase + c]),
                        fmaxf(colbuf[2][cbase + c], colbuf[3][cbase + c]));
        ssum += m;
      }
    }
    ssum += __shfl_xor(ssum, 1);
    ssum += __shfl_xor(ssum, 2);
    ssum += __shfl_xor(ssum, 4);
    ssum += __shfl_xor(ssum, 8);
    ssum += __shfl_xor(ssum, 16);
    ssum += __shfl_xor(ssum, 32);
    if (lane == 0) {
      float rs = rowsum_lds[0][wave] + rowsum_lds[1][wave] +
                 rowsum_lds[2][wave] + rowsum_lds[3][wave];
      t2v[b * NQ + q] = ssum / (float)len;
      v2t[b * NQ + q] = rs / (float)NV;
    }
  }
}

// ---------------------------------------------------------------------------
extern "C" void kernel_launch(void* const* d_in, const int* in_sizes, int n_in,
                              void* d_out, int out_size, void* d_ws, size_t ws_size,
                              hipStream_t stream) {
  (void)in_sizes; (void)n_in; (void)out_size; (void)ws_size;
  const float* visual_cls     = (const float*)d_in[0];
  const float* visual_tokens  = (const float*)d_in[1];
  const float* textual_cls    = (const float*)d_in[2];
  const float* textual_tokens = (const float*)d_in[3];
  const float* Wv_cls = (const float*)d_in[4];
  const float* bv_cls = (const float*)d_in[5];
  const float* Wt_cls = (const float*)d_in[6];
  const float* bt_cls = (const float*)d_in[7];
  const float* Wv_tok = (const float*)d_in[8];
  const float* bv_tok = (const float*)d_in[9];
  const float* Wt_tok = (const float*)d_in[10];
  const float* bt_tok = (const float*)d_in[11];
  const int* text_length = (const int*)d_in[12];

  float* out = (float*)d_out;
  float* v_cls_o = out;
  float* t_cls_o = out + 49152;
  float* t2v_o   = out + 98304;
  float* v2t_o   = out + 107520;

  char* ws = (char*)d_ws;
  unsigned short* Wvb = (unsigned short*)(ws);
  unsigned short* Wtb = (unsigned short*)(ws + 786432);
  unsigned short* Yv  = (unsigned short*)(ws + 1572864);
  unsigned short* Yt  = (unsigned short*)(ws + 20938752);

  cvt_bf16_kernel<<<384, 256, 0, stream>>>(Wv_tok, Wvb, 98304);
  cvt_bf16_kernel<<<384, 256, 0, stream>>>(Wt_tok, Wtb, 98304);

  cls_kernel<<<NB, 256, 0, stream>>>(visual_cls, Wv_cls, bv_cls, v_cls_o);
  cls_kernel<<<NQ, 256, 0, stream>>>(textual_cls, Wt_cls, bt_cls, t_cls_o);

  proj_norm_kernel<<<296, 256, 0, stream>>>(visual_tokens, Wvb, bv_tok, Yv, NB * NV);
  proj_norm_kernel<<<116, 256, 0, stream>>>(textual_tokens, Wtb, bt_tok, Yt, NQ * NT);

  score_kernel<<<(NB * NQ) / 2, 256, 0, stream>>>(Yv, Yt, text_length, t2v_o, v2t_o);
}

// Round 4
// 439.517 us; speedup vs baseline: 1.5624x; 1.1240x over previous
//
#include <hip/hip_runtime.h>

// Problem constants
#define NB 96
#define NQ 96
#define NV 197
#define NT 77
#define DK 768
#define DE 512

typedef __attribute__((ext_vector_type(8))) short s16x8;
typedef __attribute__((ext_vector_type(4))) float f32x4;

__device__ __forceinline__ unsigned short f2bf(float f) {
  union { float f; unsigned int u; } v; v.f = f;
  unsigned int u = v.u;
  unsigned int r = u + 0x7fffu + ((u >> 16) & 1u);
  return (unsigned short)(r >> 16);
}

__device__ __forceinline__ unsigned int pack2bf(float a, float b) {
  return (unsigned int)f2bf(a) | ((unsigned int)f2bf(b) << 16);
}

// global -> LDS direct, 16B/lane.  LDS dest = uniform base + lane*16.
// off must be a compile-time constant (13-bit signed, bytes).
#define GL16(gp, lp, off)                                                \
  __builtin_amdgcn_global_load_lds(                                      \
      (const __attribute__((address_space(1))) void*)(gp),               \
      (__attribute__((address_space(3))) void*)(lp), 16, (off), 0)

// ---------------------------------------------------------------------------
// K_prep: fused  cvt(Wv) | cvt(Wt) | cls_v | cls_t   via blockIdx ranges.
// ---------------------------------------------------------------------------
__global__ __launch_bounds__(256) void prep_kernel(
    const float* __restrict__ Wv_tok, unsigned short* __restrict__ Wvb,
    const float* __restrict__ Wt_tok, unsigned short* __restrict__ Wtb,
    const float* __restrict__ visual_cls, const float* __restrict__ Wv_cls,
    const float* __restrict__ bv_cls, float* __restrict__ v_cls_o,
    const float* __restrict__ textual_cls, const float* __restrict__ Wt_cls,
    const float* __restrict__ bt_cls, float* __restrict__ t_cls_o) {
  __shared__ float xs[DK];
  const int blk = blockIdx.x;
  const int tid = threadIdx.x;

  if (blk < 768) {
    // cvt: 384 blocks each for Wv, Wt (98304 float4 each)
    const float* src = (blk < 384) ? Wv_tok : Wt_tok;
    unsigned short* dst = (blk < 384) ? Wvb : Wtb;
    int i = ((blk < 384) ? blk : (blk - 384)) * 256 + tid;
    float4 x = ((const float4*)src)[i];
    ushort4 h;
    h.x = f2bf(x.x); h.y = f2bf(x.y); h.z = f2bf(x.z); h.w = f2bf(x.w);
    ((ushort4*)dst)[i] = h;
    return;
  }
  // cls: 96 blocks visual, 96 blocks textual
  const int is_t = (blk >= 864);
  const int row = blk - (is_t ? 864 : 768);
  const float* X = is_t ? textual_cls : visual_cls;
  const float* W = is_t ? Wt_cls : Wv_cls;
  const float* bias = is_t ? bt_cls : bv_cls;
  float* out = is_t ? t_cls_o : v_cls_o;

  const float* xr = X + (long)row * DK;
  for (int i = tid; i < DK; i += 256) xs[i] = xr[i];
  __syncthreads();
  for (int c = tid; c < DE; c += 256) {
    const float* wr = W + (long)c * DK;
    float s = 0.f;
    #pragma unroll 4
    for (int k = 0; k < DK; k += 4) {
      float4 w4 = *(const float4*)(wr + k);
      s += xs[k] * w4.x + xs[k + 1] * w4.y + xs[k + 2] * w4.z + xs[k + 3] * w4.w;
    }
    out[(long)row * DE + c] = s + bias[c];
  }
}

// ---------------------------------------------------------------------------
// K_proj: fused token projection + bias + l2norm for BOTH modalities.
// Blocks 0..295 -> visual (M=18912); 296..411 -> textual (M=7392).
// Block = 64 rows x 512 cols.  K-chunk 64, 12 iters.
// ---------------------------------------------------------------------------
__global__ __launch_bounds__(256, 2) void proj_norm_kernel(
    const float* __restrict__ Xv, const unsigned short* __restrict__ Wvb,
    const float* __restrict__ bv, unsigned short* __restrict__ Yv,
    const float* __restrict__ Xt, const unsigned short* __restrict__ Wtb,
    const float* __restrict__ bt, unsigned short* __restrict__ Yt) {
  __shared__ __align__(16) unsigned short Ws[512 * 64];  // 65536 B
  __shared__ __align__(16) unsigned short Xs[64 * 64];   // 8192 B
  __shared__ float ssq_lds[4][64];

  const int blk = blockIdx.x;
  const int is_t = (blk >= 296);
  const float* X = is_t ? Xt : Xv;
  const unsigned short* Wb = is_t ? Wtb : Wvb;
  const float* bias = is_t ? bt : bv;
  unsigned short* Y = is_t ? Yt : Yv;
  const int M = is_t ? (NQ * NT) : (NB * NV);
  const long row0 = (long)(is_t ? (blk - 296) : blk) * 64;

  const int tid = threadIdx.x;
  const int wave = tid >> 6;
  const int lane = tid & 63;
  const int l15 = lane & 15;
  const int quad = lane >> 4;

  const int sub = lane >> 3;                 // 0..7
  const int swz = ((lane & 7) ^ sub) << 3;   // element offset
  const unsigned short* pw_base = Wb + (long)(wave * 8 + sub) * DK + swz;

  const int xrow_a = tid >> 3;               // 0..31
  const int xrow_b = xrow_a + 32;            // 32..63
  const int xs8 = tid & 7;
  long gra = row0 + xrow_a; if (gra > M - 1) gra = M - 1;
  long grb = row0 + xrow_b; if (grb > M - 1) grb = M - 1;
  const float* px_a = X + gra * DK + xs8 * 8;
  const float* px_b = X + grb * DK + xs8 * 8;
  const int xaddr_a = (xrow_a << 6) + ((xs8 ^ (xrow_a & 7)) << 3);
  const int xaddr_b = (xrow_b << 6) + ((xs8 ^ (xrow_b & 7)) << 3);

  f32x4 acc[4][8];
  #pragma unroll
  for (int m = 0; m < 4; ++m)
    #pragma unroll
    for (int n = 0; n < 8; ++n)
      acc[m][n] = (f32x4){0.f, 0.f, 0.f, 0.f};

  for (int kc = 0; kc < DK; kc += 64) {
    __syncthreads();
    {
      float4 x0 = *(const float4*)(px_a);
      float4 x1 = *(const float4*)(px_a + 4);
      uint4 h;
      h.x = pack2bf(x0.x, x0.y); h.y = pack2bf(x0.z, x0.w);
      h.z = pack2bf(x1.x, x1.y); h.w = pack2bf(x1.z, x1.w);
      *(uint4*)(&Xs[xaddr_a]) = h;
      x0 = *(const float4*)(px_b);
      x1 = *(const float4*)(px_b + 4);
      h.x = pack2bf(x0.x, x0.y); h.y = pack2bf(x0.z, x0.w);
      h.z = pack2bf(x1.x, x1.y); h.w = pack2bf(x1.z, x1.w);
      *(uint4*)(&Xs[xaddr_b]) = h;
      px_a += 64; px_b += 64;
    }
    {
      const unsigned short* pw = pw_base;
      #pragma unroll
      for (int j = 0; j < 16; ++j) {
        GL16(pw, &Ws[(j * 4 + wave) << 9], 0);
        pw += 32 * DK;
      }
      pw_base += 64;
    }
    __syncthreads();
    #pragma unroll
    for (int ks = 0; ks < 2; ++ks) {
      s16x8 af[4];
      #pragma unroll
      for (int mi = 0; mi < 4; ++mi) {
        int arow = mi * 16 + l15;
        af[mi] = *(const s16x8*)&Xs[(arow << 6) + ((((ks << 2) + quad) ^ (arow & 7)) << 3)];
      }
      #pragma unroll
      for (int nt = 0; nt < 8; ++nt) {
        int wrow = wave * 128 + nt * 16 + l15;
        s16x8 bfr = *(const s16x8*)&Ws[(wrow << 6) + ((((ks << 2) + quad) ^ (wrow & 7)) << 3)];
        #pragma unroll
        for (int mi = 0; mi < 4; ++mi)
          acc[mi][nt] = __builtin_amdgcn_mfma_f32_16x16x32_bf16(af[mi], bfr, acc[mi][nt], 0, 0, 0);
      }
    }
  }

  #pragma unroll
  for (int nt = 0; nt < 8; ++nt) {
    float bc = bias[wave * 128 + nt * 16 + l15];
    #pragma unroll
    for (int mi = 0; mi < 4; ++mi) {
      acc[mi][nt].x += bc; acc[mi][nt].y += bc; acc[mi][nt].z += bc; acc[mi][nt].w += bc;
    }
  }

  #pragma unroll
  for (int mi = 0; mi < 4; ++mi)
    #pragma unroll
    for (int r = 0; r < 4; ++r) {
      float t = 0.f;
      #pragma unroll
      for (int nt = 0; nt < 8; ++nt) { float v = acc[mi][nt][r]; t += v * v; }
      t += __shfl_xor(t, 1);
      t += __shfl_xor(t, 2);
      t += __shfl_xor(t, 4);
      t += __shfl_xor(t, 8);
      if (l15 == 0) ssq_lds[wave][mi * 16 + quad * 4 + r] = t;
    }
  __syncthreads();

  #pragma unroll
  for (int mi = 0; mi < 4; ++mi) {
    #pragma unroll
    for (int r = 0; r < 4; ++r) {
      int rr = mi * 16 + quad * 4 + r;
      float tot = ssq_lds[0][rr] + ssq_lds[1][rr] + ssq_lds[2][rr] + ssq_lds[3][rr];
      float scale = 1.f / fmaxf(sqrtf(tot), 1e-12f);
      long grow = row0 + rr;
      if (grow < M) {
        #pragma unroll
        for (int nt = 0; nt < 8; ++nt) {
          int col = wave * 128 + nt * 16 + l15;
          Y[grow * DE + col] = f2bf(acc[mi][nt][r] * scale);
        }
      }
    }
  }
}

// ---------------------------------------------------------------------------
// K3: fused similarity + masked max/sum reductions.  DOUBLE-BUFFERED.
// One block per (b, q-pair).  K-chunk 32, 16 unrolled iters:
//   barrier -> stage(next buf, async GL16) -> compute(cur buf)
// LDS layout: pair-interleaved units (2 rows per 128 B), slot =
//   ((kseg ^ (unit&3)) * 2 + (row&1)) * 16 B  -> 2 lanes / 4-bank span.
// ---------------------------------------------------------------------------
__global__ __launch_bounds__(256, 2) void score_kernel(
    const unsigned short* __restrict__ Yv, const unsigned short* __restrict__ Yt,
    const int* __restrict__ tlen, float* __restrict__ t2v, float* __restrict__ v2t) {
  __shared__ __align__(16) unsigned short As[2][104 * 64];  // 2 x 13312 B
  __shared__ __align__(16) unsigned short Bs[2][80 * 64];   // 2 x 10240 B
  __shared__ float colbuf[4][160];
  __shared__ float rowsum_lds[4][2];

  const int tid = threadIdx.x;
  const int wave = tid >> 6;
  const int lane = tid & 63;
  const int l15 = lane & 15;
  const int quad = lane >> 4;

  // XCD-locality swizzle: b fixed per XCD while qi sweeps.
  const int idx = blockIdx.x;
  const int span = idx / 384;          // 0..11
  const int r0 = idx - span * 384;
  const int b = span * 8 + (r0 & 7);
  const int qi = r0 >> 3;              // 0..47
  const int q0 = qi * 2;

  const unsigned short* Ab = Yv + (long)b * (NV * DE);
  const unsigned short* Bb = Yt + (long)q0 * (NT * DE);

  // ---- k-invariant staging pointers ----
  // segment s covers units s*8 .. s*8+7; lane: unit_local=lane>>3, slot=lane&7
  // row = unit*2 + (slot&1); kseg = (slot>>1) ^ (unit&3)
  const int ul = lane >> 3;
  const int slot = lane & 7;
  const int kseg = ((slot >> 1) ^ (ul & 3)) << 3;  // element offset
  const unsigned short* pA[4];
  #pragma unroll
  for (int j = 0; j < 4; ++j) {
    int s = wave + j * 4;                       // 0..15 (we use s<13)
    int row = (s * 8 + ul) * 2 + (slot & 1);
    if (row > NV - 1) row = NV - 1;
    pA[j] = Ab + row * DE + kseg;
  }
  const unsigned short* pB[3];
  #pragma unroll
  for (int j = 0; j < 3; ++j) {
    int s = (j < 2) ? (wave + j * 4) : (wave + 8);  // s: wave, wave+4, wave+8
    int r = (s * 8 + ul) * 2 + (slot & 1);          // 0..159 for s<10
    int half = (r >= 80) ? 1 : 0;
    int t = r - 80 * half;
    if (t > NT - 1) t = NT - 1;
    pB[j] = Bb + (long)half * (NT * DE) + t * DE + kseg;
  }

  // ---- k-invariant LDS fragment offsets (elements) ----
  // elem = unit*64 + ((quad ^ (unit&3))<<4) + ((row&1)<<3)
  int aoff[4], boff[10];
  #pragma unroll
  for (int i = 0; i < 4; ++i) {
    int arow = (wave + i * 4) * 16 + l15;
    int u = arow >> 1;
    aoff[i] = (u << 6) + (((quad ^ (u & 3)) << 4)) + ((arow & 1) << 3);
  }
  #pragma unroll
  for (int nt = 0; nt < 10; ++nt) {
    int brow = nt * 16 + l15;
    int u = brow >> 1;
    boff[nt] = (u << 6) + (((quad ^ (u & 3)) << 4)) + ((brow & 1) << 3);
  }

  f32x4 acc[4][10];
  #pragma unroll
  for (int i = 0; i < 4; ++i)
    #pragma unroll
    for (int nt = 0; nt < 10; ++nt)
      acc[i][nt] = (f32x4){0.f, 0.f, 0.f, 0.f};

  auto do_compute = [&](int p) {
    s16x8 bf[10];
    #pragma unroll
    for (int nt = 0; nt < 10; ++nt)
      bf[nt] = *(const s16x8*)&Bs[p][boff[nt]];
    #pragma unroll
    for (int i = 0; i < 4; ++i) {
      int mt = wave + (i << 2);
      if (mt < 13) {
        s16x8 af = *(const s16x8*)&As[p][aoff[i]];
        #pragma unroll
        for (int nt = 0; nt < 10; ++nt)
          acc[i][nt] = __builtin_amdgcn_mfma_f32_16x16x32_bf16(af, bf[nt], acc[i][nt], 0, 0, 0);
      }
    }
  };

  // stage K-chunk (32 elems = 64 B per row) at byte offset KB into buffer p
#define SCORE_STAGE(p, KB)                                               \
  {                                                                      \
    _Pragma("unroll")                                                    \
    for (int j = 0; j < 3; ++j)                                          \
      GL16(pA[j], &As[p][(wave + j * 4) << 9], KB);                      \
    if (wave == 0)                                                       \
      GL16(pA[3], &As[p][12 << 9], KB);                                  \
    _Pragma("unroll")                                                    \
    for (int j = 0; j < 2; ++j)                                          \
      GL16(pB[j], &Bs[p][(wave + j * 4) << 9], KB);                      \
    if (wave < 2)                                                        \
      GL16(pB[2], &Bs[p][(wave + 8) << 9], KB);                          \
  }

#define SCORE_ITER(cur, KB_NEXT)                                         \
  {                                                                      \
    __syncthreads();                                                     \
    if ((KB_NEXT) < 1024) SCORE_STAGE(1 - (cur), KB_NEXT);               \
    do_compute(cur);                                                     \
  }

  SCORE_STAGE(0, 0)       // prologue
  SCORE_ITER(0, 64)
  SCORE_ITER(1, 128)
  SCORE_ITER(0, 192)
  SCORE_ITER(1, 256)
  SCORE_ITER(0, 320)
  SCORE_ITER(1, 384)
  SCORE_ITER(0, 448)
  SCORE_ITER(1, 512)
  SCORE_ITER(0, 576)
  SCORE_ITER(1, 640)
  SCORE_ITER(0, 704)
  SCORE_ITER(1, 768)
  SCORE_ITER(0, 832)
  SCORE_ITER(1, 896)
  SCORE_ITER(0, 960)
  SCORE_ITER(1, 1024)     // last: no stage

#undef SCORE_ITER
#undef SCORE_STAGE

  const int len0 = tlen[q0];
  const int len1 = tlen[q0 + 1];

  // ---- column max over valid v rows (t2v path), both q halves ----
  #pragma unroll
  for (int nt = 0; nt < 10; ++nt) {
    float m = -1e30f;
    #pragma unroll
    for (int i = 0; i < 4; ++i) {
      int mt = wave + (i << 2);
      if (mt < 13) {
        int mbase = mt * 16 + quad * 4;
        #pragma unroll
        for (int r = 0; r < 4; ++r)
          if (mbase + r < NV) m = fmaxf(m, acc[i][nt][r]);
      }
    }
    m = fmaxf(m, __shfl_xor(m, 16));
    m = fmaxf(m, __shfl_xor(m, 32));
    if (lane < 16) colbuf[wave][nt * 16 + l15] = m;
  }

  // ---- row max over valid t cols (v2t path), per q half ----
  float psum[2] = {0.f, 0.f};
  #pragma unroll
  for (int h = 0; h < 2; ++h) {
    int len = h ? len1 : len0;
    #pragma unroll
    for (int i = 0; i < 4; ++i) {
      int mt = wave + (i << 2);
      if (mt < 13) {
        int mbase = mt * 16 + quad * 4;
        #pragma unroll
        for (int r = 0; r < 4; ++r) {
          float rm = -1e30f;
          #pragma unroll
          for (int nt = 0; nt < 5; ++nt) {
            int c = nt * 16 + l15;
            if (c < len) rm = fmaxf(rm, acc[i][h * 5 + nt][r]);
          }
          rm = fmaxf(rm, __shfl_xor(rm, 1));
          rm = fmaxf(rm, __shfl_xor(rm, 2));
          rm = fmaxf(rm, __shfl_xor(rm, 4));
          rm = fmaxf(rm, __shfl_xor(rm, 8));
          if (len < NT) rm = fmaxf(rm, 0.f);  // masked zeros participate in max
          if (l15 == 0 && (mbase + r) < NV) psum[h] += rm;
        }
      }
    }
    psum[h] += __shfl_xor(psum[h], 16);
    psum[h] += __shfl_xor(psum[h], 32);
  }
  if (lane == 0) { rowsum_lds[wave][0] = psum[0]; rowsum_lds[wave][1] = psum[1]; }
  __syncthreads();

  if (wave < 2) {
    int q = q0 + wave;
    int len = wave ? len1 : len0;
    int cbase = wave * 80;
    float ssum = 0.f;
    for (int c = lane; c < 80; c += 64) {
      if (c < len) {
        float m = fmaxf(fmaxf(colbuf[0][cbase + c], colbuf[1][cbase + c]),
                        fmaxf(colbuf[2][cbase + c], colbuf[3][cbase + c]));
        ssum += m;
      }
    }
    ssum += __shfl_xor(ssum, 1);
    ssum += __shfl_xor(ssum, 2);
    ssum += __shfl_xor(ssum, 4);
    ssum += __shfl_xor(ssum, 8);
    ssum += __shfl_xor(ssum, 16);
    ssum += __shfl_xor(ssum, 32);
    if (lane == 0) {
      float rs = rowsum_lds[0][wave] + rowsum_lds[1][wave] +
                 rowsum_lds[2][wave] + rowsum_lds[3][wave];
      t2v[b * NQ + q] = ssum / (float)len;
      v2t[b * NQ + q] = rs / (float)NV;
    }
  }
}

// ---------------------------------------------------------------------------
extern "C" void kernel_launch(void* const* d_in, const int* in_sizes, int n_in,
                              void* d_out, int out_size, void* d_ws, size_t ws_size,
                              hipStream_t stream) {
  (void)in_sizes; (void)n_in; (void)out_size; (void)ws_size;
  const float* visual_cls     = (const float*)d_in[0];
  const float* visual_tokens  = (const float*)d_in[1];
  const float* textual_cls    = (const float*)d_in[2];
  const float* textual_tokens = (const float*)d_in[3];
  const float* Wv_cls = (const float*)d_in[4];
  const float* bv_cls = (const float*)d_in[5];
  const float* Wt_cls = (const float*)d_in[6];
  const float* bt_cls = (const float*)d_in[7];
  const float* Wv_tok = (const float*)d_in[8];
  const float* bv_tok = (const float*)d_in[9];
  const float* Wt_tok = (const float*)d_in[10];
  const float* bt_tok = (const float*)d_in[11];
  const int* text_length = (const int*)d_in[12];

  float* out = (float*)d_out;
  float* v_cls_o = out;
  float* t_cls_o = out + 49152;
  float* t2v_o   = out + 98304;
  float* v2t_o   = out + 107520;

  char* ws = (char*)d_ws;
  unsigned short* Wvb = (unsigned short*)(ws);
  unsigned short* Wtb = (unsigned short*)(ws + 786432);
  unsigned short* Yv  = (unsigned short*)(ws + 1572864);
  unsigned short* Yt  = (unsigned short*)(ws + 20938752);

  prep_kernel<<<960, 256, 0, stream>>>(
      Wv_tok, Wvb, Wt_tok, Wtb,
      visual_cls, Wv_cls, bv_cls, v_cls_o,
      textual_cls, Wt_cls, bt_cls, t_cls_o);

  proj_norm_kernel<<<412, 256, 0, stream>>>(
      visual_tokens, Wvb, bv_tok, Yv,
      textual_tokens, Wtb, bt_tok, Yt);

  score_kernel<<<(NB * NQ) / 2, 256, 0, stream>>>(Yv, Yt, text_length, t2v_o, v2t_o);
}